// Round 8
// baseline (209.702 us; speedup 1.0000x reference)
//
#include <hip/hip_runtime.h>

typedef __bf16 bf16;
typedef __bf16 bf16x4 __attribute__((ext_vector_type(4)));
typedef __bf16 bf16x8 __attribute__((ext_vector_type(8)));
typedef float f32x4 __attribute__((ext_vector_type(4)));

#define SEQ 4096
#define EMB 1024

// async global->LDS, 16B per lane; LDS dest = wave-uniform base + lane*16 (m97/m104)
__device__ __forceinline__ void async_copy16(void* lds, const void* g) {
    __builtin_amdgcn_global_load_lds(
        (const __attribute__((address_space(1))) unsigned int*)g,
        (__attribute__((address_space(3))) unsigned int*)lds,
        16, 0, 0);
}

// One prep kernel: fp32->bf16 of x, W_Q|W_K (stacked), W_V; zero rowsum.
__global__ __launch_bounds__(256) void prep_all(const float* __restrict__ x,
                                                const float* __restrict__ wq,
                                                const float* __restrict__ wk,
                                                const float* __restrict__ wv,
                                                bf16* __restrict__ xb,
                                                bf16* __restrict__ wqk,
                                                bf16* __restrict__ wvb,
                                                float* __restrict__ rowsum)
{
    const int u = blockIdx.x * 256 + threadIdx.x;
    const float* src;
    bf16* dst;
    int off;
    if (u < 1048576)      { src = x;  dst = xb;               off = u; }
    else if (u < 1310720) { src = wq; dst = wqk;              off = u - 1048576; }
    else if (u < 1572864) { src = wk; dst = wqk + EMB * EMB;  off = u - 1310720; }
    else if (u < 1835008) { src = wv; dst = wvb;              off = u - 1572864; }
    else {                // u < 1836032: zero rowsum[4096]
        *(float4*)(rowsum + (size_t)(u - 1835008) * 4) = float4{0.f, 0.f, 0.f, 0.f};
        return;
    }
    float4 f = *(const float4*)(src + (size_t)off * 4);
    bf16x4 v = { (bf16)f.x, (bf16)f.y, (bf16)f.z, (bf16)f.w };
    *(bf16x4*)(dst + (size_t)off * 4) = v;
}

// ---------------------------------------------------------------------------
// 256x256 tile, BK=64, NT=16, 512 threads = 8 waves (2 m x 4 n), per-wave
// output 128x64. m201-port: 8-phase (2 groups of 4) schedule with HALF-TILE
// rotation staging -- 2 global_load_lds in EVERY phase (fine ds||G||MFMA
// interleave, m196's lever), ONE counted vmcnt(4) per 4-phase group, drains
// only at group 14. LDS: As[2][16384] + Bs[2][16384] bf16 = 128 KiB
// (dbuf d holds K-tile of parity d).
// Group g (reads dbuf d=g&1), phases:
//  ph1: stage A(g+1)h0 -> dbuf d^1 | read A-mg0 (8 b128) + B-ngh0 (4);
//       barrier; lgkm(0); setprio(1) 16 MFMA (mg0 x ngh0) setprio(0); barrier
//  ph2: stage A(g+1)h1 | read B-ngh1 (4); ... MFMA (mg0 x ngh1)
//  ph3: stage B(g+2)h0 -> dbuf d    | read A-mg1 (8); ... MFMA (mg1 x ngh1)
//  ph4: stage B(g+2)h1 | vmcnt(4); barrier; MFMA (mg1 x ngh0); barrier
// Safety (all barrier-proven): A(g+1) overwrites slot last read g-1.ph3;
// B(g+2) overwrites B(g), last read g.ph2. vmcnt(4) at g.ph4 completes
// B(g+1) [staged g-1.ph3/4] + A(g+1) [g.ph1/2] => tile g+1 resident for
// group g+1.  Prologue: tile0 (8 loads) + B(1) (4 loads), vmcnt(4).
// Rotation swizzle (chunk+row)&7 both sides (R0-verified, 0 conflicts):
// row stride 64 elems (128B); lane q reads logical chunk q / q+4 at physical
// ((q+fr)&7) / ^4; staging lane (srow,spc) fetches logical (spc-(srow&7))&7.
// RSUM: per-row sums of A-frags (lane fr = row; q-lanes disjoint k-chunks).
// ---------------------------------------------------------------------------
__device__ __forceinline__ void stage_half(bf16* lbase, const bf16* gbase,
                                           int ldx, int t, int h) {
    const bf16* g = gbase + t * 64 + (size_t)(h * 128) * ldx;
    bf16* l = lbase + h * 8192;
    async_copy16(l,        g);
    async_copy16(l + 4096, g + (size_t)64 * ldx);
}

__device__ __forceinline__ void quad_mfma(bf16x8 (&af)[4][2], bf16x8 (&bg)[2][2],
                                          f32x4 (&acc)[8][4], int mg, int ngh)
{
#pragma unroll
    for (int nj = 0; nj < 2; nj++)
#pragma unroll
        for (int mf = 0; mf < 4; mf++) {
            f32x4 c = acc[mg * 4 + mf][ngh * 2 + nj];
            c = __builtin_amdgcn_mfma_f32_16x16x32_bf16(af[mf][0], bg[nj][0], c, 0, 0, 0);
            c = __builtin_amdgcn_mfma_f32_16x16x32_bf16(af[mf][1], bg[nj][1], c, 0, 0, 0);
            acc[mg * 4 + mf][ngh * 2 + nj] = c;
        }
}

__device__ __forceinline__ void rsum_add(bf16x8 (&af)[4][2], float (&rsum)[8], int mg)
{
#pragma unroll
    for (int mf = 0; mf < 4; mf++)
#pragma unroll
        for (int kh = 0; kh < 2; kh++)
#pragma unroll
            for (int e = 0; e < 8; e++)
                rsum[mg * 4 + mf] += (float)af[mf][kh][e];
}

// VMN: 4 = steady counted wait, 0 = tail drain, -1 = none
template<bool RSUM, bool STGA, bool STGB, int VMN>
__device__ __forceinline__ void group4(int g,
    const bf16* Ard, const bf16* Brd,     // LDS read bases (dbuf d = g&1)
    bf16* AwH, bf16* BwH,                 // per-thread stage bases: A->d^1, B->d
    const bf16* Ab, const bf16* Bb, int lda, int ldb,
    int wr, int wc, int fr, int pc0, int pc1,
    f32x4 (&acc)[8][4], float (&rsum)[8], bool rs_active)
{
    bf16x8 af[4][2], bg0[2][2], bg1[2][2];
    const bf16* Arow = Ard + (wr * 128 + fr) * 64;
    const bf16* Brow = Brd + (wc * 64 + fr) * 64;

    // ---- ph1: stage A(g+1)h0 | read A-mg0 + B-ngh0 | MFMA mg0 x ngh0
    if (STGA) stage_half(AwH, Ab, lda, g + 1, 0);
#pragma unroll
    for (int mf = 0; mf < 4; mf++) {
        af[mf][0] = *(const bf16x8*)(Arow + mf * 1024 + pc0);
        af[mf][1] = *(const bf16x8*)(Arow + mf * 1024 + pc1);
    }
#pragma unroll
    for (int nj = 0; nj < 2; nj++) {
        bg0[nj][0] = *(const bf16x8*)(Brow + nj * 1024 + pc0);
        bg0[nj][1] = *(const bf16x8*)(Brow + nj * 1024 + pc1);
    }
    asm volatile("" ::: "memory");
    __builtin_amdgcn_s_barrier();
    asm volatile("s_waitcnt lgkmcnt(0)" ::: "memory");
    __builtin_amdgcn_sched_barrier(0);
    __builtin_amdgcn_s_setprio(1);
    quad_mfma(af, bg0, acc, 0, 0);
    __builtin_amdgcn_s_setprio(0);
    if (RSUM && rs_active) rsum_add(af, rsum, 0);
    asm volatile("" ::: "memory");
    __builtin_amdgcn_s_barrier();

    // ---- ph2: stage A(g+1)h1 | read B-ngh1 | MFMA mg0 x ngh1
    if (STGA) stage_half(AwH, Ab, lda, g + 1, 1);
#pragma unroll
    for (int nj = 0; nj < 2; nj++) {
        bg1[nj][0] = *(const bf16x8*)(Brow + (2 + nj) * 1024 + pc0);
        bg1[nj][1] = *(const bf16x8*)(Brow + (2 + nj) * 1024 + pc1);
    }
    asm volatile("" ::: "memory");
    __builtin_amdgcn_s_barrier();
    asm volatile("s_waitcnt lgkmcnt(0)" ::: "memory");
    __builtin_amdgcn_sched_barrier(0);
    __builtin_amdgcn_s_setprio(1);
    quad_mfma(af, bg1, acc, 0, 1);
    __builtin_amdgcn_s_setprio(0);
    asm volatile("" ::: "memory");
    __builtin_amdgcn_s_barrier();

    // ---- ph3: stage B(g+2)h0 | read A-mg1 | MFMA mg1 x ngh1
    if (STGB) stage_half(BwH, Bb, ldb, g + 2, 0);
#pragma unroll
    for (int mf = 0; mf < 4; mf++) {
        af[mf][0] = *(const bf16x8*)(Arow + 4096 + mf * 1024 + pc0);
        af[mf][1] = *(const bf16x8*)(Arow + 4096 + mf * 1024 + pc1);
    }
    asm volatile("" ::: "memory");
    __builtin_amdgcn_s_barrier();
    asm volatile("s_waitcnt lgkmcnt(0)" ::: "memory");
    __builtin_amdgcn_sched_barrier(0);
    __builtin_amdgcn_s_setprio(1);
    quad_mfma(af, bg1, acc, 1, 1);
    __builtin_amdgcn_s_setprio(0);
    if (RSUM && rs_active) rsum_add(af, rsum, 1);
    asm volatile("" ::: "memory");
    __builtin_amdgcn_s_barrier();

    // ---- ph4: stage B(g+2)h1 | vmcnt | MFMA mg1 x ngh0
    if (STGB) stage_half(BwH, Bb, ldb, g + 2, 1);
    if constexpr (VMN == 4) { asm volatile("s_waitcnt vmcnt(4)" ::: "memory"); }
    else if constexpr (VMN == 0) { asm volatile("s_waitcnt vmcnt(0)" ::: "memory"); }
    asm volatile("" ::: "memory");
    __builtin_amdgcn_s_barrier();
    __builtin_amdgcn_sched_barrier(0);
    __builtin_amdgcn_s_setprio(1);
    quad_mfma(af, bg0, acc, 1, 0);
    __builtin_amdgcn_s_setprio(0);
    asm volatile("" ::: "memory");
    __builtin_amdgcn_s_barrier();
}

// K is fixed at 1024 for every call site (pv slices via koff) -> NT=16 groups.
template<bool RSUM>
__device__ __forceinline__ void gemm_core256(const bf16* __restrict__ A,
                                             const bf16* __restrict__ B,
                                             int lda, int ldb, long koff,
                                             int m0, int n0,
                                             bf16* __restrict__ As,  // [2][16384]
                                             bf16* __restrict__ Bs,  // [2][16384]
                                             f32x4 (&acc)[8][4], float (&rsum)[8],
                                             bool rs_active)
{
    const int tid  = threadIdx.x;
    const int lane = tid & 63;
    const int wave = tid >> 6;
    const int wr = wave >> 2;                  // 0..1 m-wave
    const int wc = wave & 3;                   // 0..3 n-wave
    const int srow = tid >> 3;                 // staging row 0..63
    const int spc  = tid & 7;                  // physical chunk (fixed by glds)
    const int sl   = (spc - (srow & 7)) & 7;   // logical chunk this lane fetches
    const int fr = lane & 15;
    const int q  = lane >> 4;
    const int pc0 = ((q + fr) & 7) * 8;        // physical chunk of logical q
    const int pc1 = pc0 ^ 32;                  // logical q+4

#pragma unroll
    for (int i = 0; i < 8; i++)
#pragma unroll
        for (int j = 0; j < 4; j++) acc[i][j] = {0.f, 0.f, 0.f, 0.f};
    if (RSUM)
#pragma unroll
        for (int i = 0; i < 8; i++) rsum[i] = 0.f;

    const bf16* Ab = A + (size_t)(m0 + srow) * lda + koff + sl * 8;
    const bf16* Bb = B + (size_t)(n0 + srow) * ldb + koff + sl * 8;
    const int soff = srow * 64 + spc * 8;

    // prologue: tile 0 fully (8 loads, oldest) + B(1) halves (4 loads)
    stage_half(As + soff,         Ab, lda, 0, 0);
    stage_half(As + soff,         Ab, lda, 0, 1);
    stage_half(Bs + soff,         Bb, ldb, 0, 0);
    stage_half(Bs + soff,         Bb, ldb, 0, 1);
    stage_half(Bs + 16384 + soff, Bb, ldb, 1, 0);
    stage_half(Bs + 16384 + soff, Bb, ldb, 1, 1);
    asm volatile("s_waitcnt vmcnt(4)" ::: "memory");   // tile 0 resident
    __builtin_amdgcn_s_barrier();

    // groups 0..13 steady (d alternates 0,1), 14 = drain, 15 = last
    for (int gg = 0; gg < 7; gg++) {
        const int g0 = 2 * gg;
        group4<RSUM, true, true, 4>(g0, As, Bs, As + 16384 + soff, Bs + soff,
                                    Ab, Bb, lda, ldb, wr, wc, fr, pc0, pc1,
                                    acc, rsum, rs_active);
        group4<RSUM, true, true, 4>(g0 + 1, As + 16384, Bs + 16384,
                                    As + soff, Bs + 16384 + soff,
                                    Ab, Bb, lda, ldb, wr, wc, fr, pc0, pc1,
                                    acc, rsum, rs_active);
    }
    group4<RSUM, true, false, 0>(14, As, Bs, As + 16384 + soff, Bs + soff,
                                 Ab, Bb, lda, ldb, wr, wc, fr, pc0, pc1,
                                 acc, rsum, rs_active);
    group4<RSUM, false, false, -1>(15, As + 16384, Bs + 16384,
                                   As + soff, Bs + 16384 + soff,
                                   Ab, Bb, lda, ldb, wr, wc, fr, pc0, pc1,
                                   acc, rsum, rs_active);
}

// Merged projections, one launch. Grid (16, 12) = 192 blocks.
// XCD swizzle (T1, hw%8 = XCD; R6: FETCH halved -> keep).
__global__ __launch_bounds__(512, 1) void gemm_proj(const bf16* __restrict__ xb,
                                                    const bf16* __restrict__ wqk,
                                                    const bf16* __restrict__ wvb,
                                                    bf16* __restrict__ QK,
                                                    bf16* __restrict__ VT)
{
    __shared__ __align__(16) bf16 As[2][16384];
    __shared__ __align__(16) bf16 Bs[2][16384];

    const int hw  = blockIdx.x + 16 * blockIdx.y;      // 0..191, dispatch order
    const int xcd = hw & 7;
    const int s   = hw >> 3;                           // 0..23
    const int bx  = ((xcd & 1) << 3) | (s & 7);        // 0..15
    const int byy = (xcd >> 1) * 3 + (s >> 3);         // 0..11

    const bf16 *A, *B;
    bf16* C;
    int ldc, m0, n0;
    if (byy < 8) {
        A = xb; B = wqk; C = QK; ldc = 2048;
        m0 = bx * 256; n0 = byy * 256;
    } else {
        const int id = bx + (byy - 8) * 16;
        A = wvb; B = xb; C = VT; ldc = 4096;
        m0 = (id & 3) * 256; n0 = (id >> 2) * 256;
    }

    f32x4 acc[8][4];
    float rs[8];
    gemm_core256<false>(A, B, 1024, 1024, 0, m0, n0, &As[0][0], &Bs[0][0], acc, rs, false);

    const int lane = threadIdx.x & 63;
    const int wave = threadIdx.x >> 6;
    const int cm = m0 + (wave >> 2) * 128 + ((lane >> 4) << 2);
    const int cn = n0 + (wave & 3) * 64 + (lane & 15);
#pragma unroll
    for (int i = 0; i < 8; i++)
#pragma unroll
        for (int j = 0; j < 4; j++)
#pragma unroll
            for (int r = 0; r < 4; r++)
                C[(size_t)(cm + i * 16 + r) * ldc + (cn + j * 16)] = (bf16)acc[i][j][r];
}

// E = exp((Q @ K^T)/32), bf16. Grid (16, 16). XCD swizzle: (8 m, 4 n)/XCD.
__global__ __launch_bounds__(512, 1) void gemm_exp(const bf16* __restrict__ QK,
                                                   bf16* __restrict__ E)
{
    __shared__ __align__(16) bf16 As[2][16384];
    __shared__ __align__(16) bf16 Bs[2][16384];

    const int hw  = blockIdx.x + 16 * blockIdx.y;      // 0..255
    const int xcd = hw & 7;
    const int s   = hw >> 3;                           // 0..31
    const int bx  = ((xcd & 1) << 3) | (s & 7);        // 0..15
    const int by  = ((xcd >> 1) << 2) | (s >> 3);      // 0..15

    const int m0 = bx * 256;
    const int n0 = by * 256;
    f32x4 acc[8][4];
    float rs[8];
    gemm_core256<false>(QK, QK + 1024, 2048, 2048, 0, m0, n0, &As[0][0], &Bs[0][0], acc, rs, false);

    const int lane = threadIdx.x & 63;
    const int wave = threadIdx.x >> 6;
    const int cm = m0 + (wave >> 2) * 128 + ((lane >> 4) << 2);
    const int cn = n0 + (wave & 3) * 64 + (lane & 15);
#pragma unroll
    for (int i = 0; i < 8; i++)
#pragma unroll
        for (int j = 0; j < 4; j++)
#pragma unroll
            for (int r = 0; r < 4; r++)
                E[(size_t)(cm + i * 16 + r) * 4096 + (cn + j * 16)] =
                    (bf16)__expf(acc[i][j][r] * 0.03125f);
}

// PV partials + rowsum-from-A-frags. Grid (16 m, 4 n, 4 z); K=1024/slice.
// XCD swizzle: each XCD owns (8 m, all 4 n, ONE z). z=0 -> out, z>=1 -> p1+..
__global__ __launch_bounds__(512, 1) void gemm_pv(const bf16* __restrict__ E,
                                                  const bf16* __restrict__ VT,
                                                  float* __restrict__ out,
                                                  float* __restrict__ p1,
                                                  float* __restrict__ rowsum)
{
    __shared__ __align__(16) bf16 As[2][16384];
    __shared__ __align__(16) bf16 Bs[2][16384];

    const int hw  = blockIdx.x + 16 * blockIdx.y + 64 * blockIdx.z;  // 0..255
    const int xcd = hw & 7;
    const int s   = hw >> 3;                           // 0..31
    const int bx  = ((xcd & 1) << 3) | (s & 7);        // 0..15
    const int by  = s >> 3;                            // 0..3
    const int bz  = xcd >> 1;                          // 0..3

    const int m0 = bx * 256;
    const int n0 = by * 256;
    const long koff = (long)bz * 1024;
    const bool rs_active = (by == 0) && (((threadIdx.x >> 6) & 3) == 0);

    f32x4 acc[8][4];
    float rs[8];
    gemm_core256<true>(E, VT, 4096, 4096, koff, m0, n0, &As[0][0], &Bs[0][0], acc, rs, rs_active);

    const int lane = threadIdx.x & 63;
    const int wave = threadIdx.x >> 6;
    if (rs_active) {
#pragma unroll
        for (int i = 0; i < 8; i++) {
            rs[i] += __shfl_xor(rs[i], 16);
            rs[i] += __shfl_xor(rs[i], 32);
        }
        if (lane < 16) {
            const int rbase = m0 + (wave >> 2) * 128;
#pragma unroll
            for (int i = 0; i < 8; i++)
                unsafeAtomicAdd(&rowsum[rbase + i * 16 + lane], rs[i]);
        }
    }

    float* C = (bz == 0) ? out : p1 + (size_t)(bz - 1) * SEQ * 1024;
    const int cm = m0 + (wave >> 2) * 128 + ((lane >> 4) << 2);
    const int cn = n0 + (wave & 3) * 64 + (lane & 15);
#pragma unroll
    for (int i = 0; i < 8; i++)
#pragma unroll
        for (int j = 0; j < 4; j++)
#pragma unroll
            for (int r = 0; r < 4; r++)
                C[(size_t)(cm + i * 16 + r) * 1024 + (cn + j * 16)] = acc[i][j][r];
}

// one block per row m: out[m] = (out[m] + p1[m] + p2[m] + p3[m]) / rowsum[m]
__global__ __launch_bounds__(256) void reduce_norm(float* __restrict__ out,
                                                   const float* __restrict__ p1,
                                                   const float* __restrict__ p2,
                                                   const float* __restrict__ p3,
                                                   const float* __restrict__ rowsum)
{
    const int m = blockIdx.x;
    const float inv = 1.f / rowsum[m];
    const size_t off = (size_t)m * 1024 + threadIdx.x * 4;
    float4 a = *(const float4*)(out + off);
    float4 b = *(const float4*)(p1 + off);
    float4 c = *(const float4*)(p2 + off);
    float4 d = *(const float4*)(p3 + off);
    float4 o;
    o.x = (a.x + b.x + c.x + d.x) * inv;
    o.y = (a.y + b.y + c.y + d.y) * inv;
    o.z = (a.z + b.z + c.z + d.z) * inv;
    o.w = (a.w + b.w + c.w + d.w) * inv;
    *(float4*)(out + off) = o;
}

extern "C" void kernel_launch(void* const* d_in, const int* in_sizes, int n_in,
                              void* d_out, int out_size, void* d_ws, size_t ws_size,
                              hipStream_t stream)
{
    const float* x  = (const float*)d_in[0];   // (4096, 1024) fp32
    const float* wq = (const float*)d_in[1];   // (1024, 1024) fp32
    const float* wk = (const float*)d_in[2];
    const float* wv = (const float*)d_in[3];
    float* out = (float*)d_out;                // (4096, 1024) fp32

    char* ws = (char*)d_ws;
    const size_t MB = 1024 * 1024;
    bf16*  E   = (bf16*)(ws);                   // [0,32)   4096x4096 bf16
    float* p1  = (float*)(ws + 32 * MB);        // [32,48)  PV partial z=1
    float* p2  = (float*)(ws + 48 * MB);        // [48,64)  PV partial z=2
    float* p3  = (float*)(ws + 64 * MB);        // [64,80)  PV partial z=3
    bf16*  xb  = (bf16*)(ws + 32 * MB);         // [32,40)  (dead before p1 written)
    bf16*  wqk = (bf16*)(ws + 40 * MB);         // [40,44)  W_Q|W_K (2048x1024)
    bf16*  wvb = (bf16*)(ws + 44 * MB);         // [44,46)
    bf16*  QK  = (bf16*)(ws + 64 * MB);         // [64,80)  4096x2048 (dead before p3)
    bf16*  VT  = (bf16*)(ws + 80 * MB);         // [80,88)  1024x4096 = V^T
    float* rsm = (float*)(ws + 88 * MB);        // [88,88+16KB) rowsum

    // 0. convert inputs to bf16 + zero rowsum
    prep_all<<<dim3(7172), dim3(256), 0, stream>>>(x, wq, wk, wv, xb, wqk, wvb, rsm);
    // 1. merged projections: QK (128 blocks) + VT (64 blocks)
    gemm_proj<<<dim3(16, 12), dim3(512), 0, stream>>>(xb, wqk, wvb, QK, VT);
    // 2. E = exp((Q @ K^T)/32)  (256 blocks = 1/CU)
    gemm_exp<<<dim3(16, 16), dim3(512), 0, stream>>>(QK, E);
    // 3. PV partials (split-K 4) + rowsum  (256 blocks = 1/CU)
    gemm_pv<<<dim3(16, 4, 4), dim3(512), 0, stream>>>(E, VT, out, p1, rsm);
    // 4. out[m] = (out + p1 + p2 + p3)[m] / rowsum[m]
    reduce_norm<<<dim3(4096), dim3(256), 0, stream>>>(out, p1, p2, p3, rsm);
}